// Round 5
// baseline (1123.282 us; speedup 1.0000x reference)
//
#include <hip/hip_runtime.h>
#include <hip/hip_bf16.h>
#include <math.h>

#define T_TOK 8192
#define HDIM  1024
#define IDIM  4096
#define SDIM  128
#define TOPK  16

typedef __bf16 bf16x8 __attribute__((ext_vector_type(8)));
typedef float  f32x4  __attribute__((ext_vector_type(4)));

__device__ __forceinline__ unsigned short f2bf(float f) {
    union { float f; unsigned u; } a; a.f = f;
    unsigned r = a.u + 0x7fffu + ((a.u >> 16) & 1u);
    return (unsigned short)(r >> 16);
}
__device__ __forceinline__ float bf2f(unsigned short b) {
    union { unsigned u; float f; } a; a.u = ((unsigned)b) << 16;
    return a.f;
}

// ---------------- merged fp32 -> bf16 convert over 8 segments ----------------
struct CvtSegs {
    const float4* src[8];
    ushort4*      dst[8];
    int           end[8];   // prefix-sum of float4 counts
};

__global__ __launch_bounds__(256)
void cvt_all_kernel(CvtSegs segs) {
    int i = blockIdx.x * 256 + threadIdx.x;
    if (i >= segs.end[7]) return;
    int s = 0;
    #pragma unroll
    for (int k = 0; k < 7; ++k) s += (i >= segs.end[k]) ? 1 : 0;
    int base = (s == 0) ? 0 : segs.end[s - 1];
    int j = i - base;
    float4 v = segs.src[s][j];
    ushort4 o;
    o.x = f2bf(v.x); o.y = f2bf(v.y); o.z = f2bf(v.z); o.w = f2bf(v.w);
    segs.dst[s][j] = o;
}

__device__ __forceinline__ bf16x8 ldfrag(const unsigned short* p) {
    return *(const bf16x8*)p;
}

// ---------------- GEMM1 (no-LDS, barrier-free) + fused router logits ----------------
// by < 64:  h = silu(x@Wg^T) * (x@Wu^T) tile  -> Hb (bf16)
// by >= 64: router logits tile x@Wr^T        -> gxy (fp32, 256 cols)
// tile 128(M) x 64(N), wave = 64x32 dual; frags loaded straight from global.
__global__ __launch_bounds__(256)
void gemm1_fused(const unsigned short* __restrict__ Xb, const unsigned short* __restrict__ Wg,
                 const unsigned short* __restrict__ Wu, const unsigned short* __restrict__ Wr,
                 unsigned short* __restrict__ Hb, float* __restrict__ gxy) {
    const int K = HDIM;
    const int tid  = threadIdx.x;
    const int lane = tid & 63;
    const int wave = tid >> 6;
    const int by   = blockIdx.y;
    const bool router = (by >= IDIM / 64);
    const int tm = blockIdx.x * 128;
    const int tn = router ? (by - IDIM / 64) * 64 : by * 64;
    const int wm = (wave & 1) * 64;
    const int wn = (wave >> 1) * 32;
    const int quad = lane >> 4;
    const int tr   = lane & 15;

    const unsigned short* Bg = router ? Wr : Wg;
    const unsigned short* Bu = router ? Wr : Wu;

    // per-lane fragment base pointers (A/B layout: lane holds row (15&l), k = quad*8..+7)
    const unsigned short* ap[4];
    const unsigned short* gp[2];
    const unsigned short* up[2];
    #pragma unroll
    for (int mi = 0; mi < 4; ++mi)
        ap[mi] = Xb + (size_t)(tm + wm + mi * 16 + tr) * K + quad * 8;
    #pragma unroll
    for (int ni = 0; ni < 2; ++ni) {
        gp[ni] = Bg + (size_t)(tn + wn + ni * 16 + tr) * K + quad * 8;
        up[ni] = Bu + (size_t)(tn + wn + ni * 16 + tr) * K + quad * 8;
    }

    f32x4 ag[4][2] = {};
    f32x4 au[4][2] = {};
    bf16x8 a0[4], g0[2], u0[2];
    bf16x8 a1[4], g1[2], u1[2];

    #pragma unroll
    for (int mi = 0; mi < 4; ++mi) a0[mi] = ldfrag(ap[mi]);
    #pragma unroll
    for (int ni = 0; ni < 2; ++ni) { g0[ni] = ldfrag(gp[ni]); u0[ni] = ldfrag(up[ni]); }

    for (int kt = 0; kt < K; kt += 64) {
        #pragma unroll
        for (int mi = 0; mi < 4; ++mi) a1[mi] = ldfrag(ap[mi] + kt + 32);
        #pragma unroll
        for (int ni = 0; ni < 2; ++ni) { g1[ni] = ldfrag(gp[ni] + kt + 32); u1[ni] = ldfrag(up[ni] + kt + 32); }
        #pragma unroll
        for (int mi = 0; mi < 4; ++mi)
            #pragma unroll
            for (int ni = 0; ni < 2; ++ni) {
                ag[mi][ni] = __builtin_amdgcn_mfma_f32_16x16x32_bf16(a0[mi], g0[ni], ag[mi][ni], 0, 0, 0);
                au[mi][ni] = __builtin_amdgcn_mfma_f32_16x16x32_bf16(a0[mi], u0[ni], au[mi][ni], 0, 0, 0);
            }
        // prefetch next (reads ≤2KB past segment end on final iter — lands in adjacent ws buffer, safe)
        #pragma unroll
        for (int mi = 0; mi < 4; ++mi) a0[mi] = ldfrag(ap[mi] + kt + 64);
        #pragma unroll
        for (int ni = 0; ni < 2; ++ni) { g0[ni] = ldfrag(gp[ni] + kt + 64); u0[ni] = ldfrag(up[ni] + kt + 64); }
        #pragma unroll
        for (int mi = 0; mi < 4; ++mi)
            #pragma unroll
            for (int ni = 0; ni < 2; ++ni) {
                ag[mi][ni] = __builtin_amdgcn_mfma_f32_16x16x32_bf16(a1[mi], g1[ni], ag[mi][ni], 0, 0, 0);
                au[mi][ni] = __builtin_amdgcn_mfma_f32_16x16x32_bf16(a1[mi], u1[ni], au[mi][ni], 0, 0, 0);
            }
    }

    if (!router) {
        #pragma unroll
        for (int mi = 0; mi < 4; ++mi)
            #pragma unroll
            for (int ni = 0; ni < 2; ++ni) {
                int col = tn + wn + ni * 16 + tr;
                #pragma unroll
                for (int r = 0; r < 4; ++r) {
                    int row = tm + wm + mi * 16 + quad * 4 + r;
                    float g = ag[mi][ni][r];
                    float u = au[mi][ni][r];
                    float h = g / (1.0f + __expf(-g)) * u;  // silu(g)*u
                    Hb[(size_t)row * IDIM + col] = f2bf(h);
                }
            }
    } else {
        #pragma unroll
        for (int mi = 0; mi < 4; ++mi)
            #pragma unroll
            for (int ni = 0; ni < 2; ++ni) {
                int col = tn + wn + ni * 16 + tr;   // [0,256)
                #pragma unroll
                for (int r = 0; r < 4; ++r) {
                    int row = tm + wm + mi * 16 + quad * 4 + r;
                    gxy[(size_t)row * 256 + col] = ag[mi][ni][r];
                }
            }
    }
}

// ---------------- GEMM2 (no-LDS, barrier-free): out += hbuf @ downb^T ----------------
// tile 128(M) x 128(N), wave = 64x64
__global__ __launch_bounds__(256)
void gemm2_add(const unsigned short* __restrict__ A, const unsigned short* __restrict__ B,
               float* __restrict__ C) {
    const int K = IDIM, N = HDIM;
    const int tid  = threadIdx.x;
    const int lane = tid & 63;
    const int wave = tid >> 6;
    const int tm = blockIdx.x * 128;
    const int tn = blockIdx.y * 128;
    const int wm = (wave & 1) * 64;
    const int wn = (wave >> 1) * 64;
    const int quad = lane >> 4;
    const int tr   = lane & 15;

    const unsigned short* ap[4];
    const unsigned short* bp[4];
    #pragma unroll
    for (int mi = 0; mi < 4; ++mi)
        ap[mi] = A + (size_t)(tm + wm + mi * 16 + tr) * K + quad * 8;
    #pragma unroll
    for (int ni = 0; ni < 4; ++ni)
        bp[ni] = B + (size_t)(tn + wn + ni * 16 + tr) * K + quad * 8;

    f32x4 acc[4][4] = {};
    bf16x8 a0[4], b0[4], a1[4], b1[4];
    #pragma unroll
    for (int mi = 0; mi < 4; ++mi) a0[mi] = ldfrag(ap[mi]);
    #pragma unroll
    for (int ni = 0; ni < 4; ++ni) b0[ni] = ldfrag(bp[ni]);

    for (int kt = 0; kt < K; kt += 64) {
        #pragma unroll
        for (int mi = 0; mi < 4; ++mi) a1[mi] = ldfrag(ap[mi] + kt + 32);
        #pragma unroll
        for (int ni = 0; ni < 4; ++ni) b1[ni] = ldfrag(bp[ni] + kt + 32);
        #pragma unroll
        for (int mi = 0; mi < 4; ++mi)
            #pragma unroll
            for (int ni = 0; ni < 4; ++ni)
                acc[mi][ni] = __builtin_amdgcn_mfma_f32_16x16x32_bf16(a0[mi], b0[ni], acc[mi][ni], 0, 0, 0);
        #pragma unroll
        for (int mi = 0; mi < 4; ++mi) a0[mi] = ldfrag(ap[mi] + kt + 64);
        #pragma unroll
        for (int ni = 0; ni < 4; ++ni) b0[ni] = ldfrag(bp[ni] + kt + 64);
        #pragma unroll
        for (int mi = 0; mi < 4; ++mi)
            #pragma unroll
            for (int ni = 0; ni < 4; ++ni)
                acc[mi][ni] = __builtin_amdgcn_mfma_f32_16x16x32_bf16(a1[mi], b1[ni], acc[mi][ni], 0, 0, 0);
    }

    #pragma unroll
    for (int mi = 0; mi < 4; ++mi)
        #pragma unroll
        for (int ni = 0; ni < 4; ++ni) {
            int col = tn + wn + ni * 16 + tr;
            #pragma unroll
            for (int r = 0; r < 4; ++r) {
                int row = tm + wm + mi * 16 + quad * 4 + r;
                size_t o = (size_t)row * N + col;
                C[o] += acc[mi][ni][r];
            }
        }
}

// ---------------- batchnorm stats ----------------
__global__ void bn_stats(const float* __restrict__ gxy, float* __restrict__ sums, float* __restrict__ ssq) {
    const int j = threadIdx.x;
    const int b = blockIdx.x;
    float s = 0.f, q = 0.f;
    for (int r = 0; r < 32; ++r) {
        float v = gxy[(size_t)(b * 32 + r) * 256 + j];
        s += v; q += v * v;
    }
    atomicAdd(&sums[j], s);
    atomicAdd(&ssq[j], q);
}

// ---------------- routing: bn -> log_softmax -> top16 via candidate reduction ----------------
__global__ __launch_bounds__(256)
void routing_kernel(const float* __restrict__ gxy, const float* __restrict__ sums,
                    const float* __restrict__ ssq, int* __restrict__ oidx, float* __restrict__ owt) {
    const int lane = threadIdx.x & 63;
    const int t = blockIdx.x * 4 + (threadIdx.x >> 6);
    const float invT = 1.0f / (float)T_TOK;
    const float* g = gxy + (size_t)t * 256;

    float z[4];
    const int cols[4] = {lane, lane + 64, 128 + lane, 192 + lane};
    #pragma unroll
    for (int i = 0; i < 4; ++i) {
        int c = cols[i];
        float mu  = sums[c] * invT;
        float var = ssq[c] * invT - mu * mu;
        z[i] = (g[c] - mu) * rsqrtf(var + 1e-5f);
    }
    float mx = fmaxf(z[0], z[1]);
    float my = fmaxf(z[2], z[3]);
    #pragma unroll
    for (int m = 32; m >= 1; m >>= 1) {
        mx = fmaxf(mx, __shfl_xor(mx, m));
        my = fmaxf(my, __shfl_xor(my, m));
    }
    float sx = __expf(z[0] - mx) + __expf(z[1] - mx);
    float sy = __expf(z[2] - my) + __expf(z[3] - my);
    #pragma unroll
    for (int m = 32; m >= 1; m >>= 1) {
        sx += __shfl_xor(sx, m);
        sy += __shfl_xor(sy, m);
    }
    float lx0 = z[0] - (mx + __logf(sx)), lx1 = z[1] - (mx + __logf(sx));
    float ly0 = z[2] - (my + __logf(sy)), ly1 = z[3] - (my + __logf(sy));

    float aw = -INFINITY; int ai = 0;
    float bw = -INFINITY; int bi = 0;
    {
        float v0 = lx0, v1 = lx1;
        for (int i = 0; i < 16; ++i) {
            float v; int c;
            if (v0 >= v1) { v = v0; c = lane; } else { v = v1; c = lane + 64; }
            #pragma unroll
            for (int m = 32; m >= 1; m >>= 1) {
                float ov = __shfl_xor(v, m); int oc = __shfl_xor(c, m);
                if (ov > v || (ov == v && oc < c)) { v = ov; c = oc; }
            }
            if ((c & 63) == lane) { if (c < 64) v0 = -INFINITY; else v1 = -INFINITY; }
            if (lane == i) { aw = v; ai = c; }
        }
    }
    {
        float v0 = ly0, v1 = ly1;
        for (int i = 0; i < 16; ++i) {
            float v; int c;
            if (v0 >= v1) { v = v0; c = lane; } else { v = v1; c = lane + 64; }
            #pragma unroll
            for (int m = 32; m >= 1; m >>= 1) {
                float ov = __shfl_xor(v, m); int oc = __shfl_xor(c, m);
                if (ov > v || (ov == v && oc < c)) { v = ov; c = oc; }
            }
            if ((c & 63) == lane) { if (c < 64) v0 = -INFINITY; else v1 = -INFINITY; }
            if (lane == i) { bw = v; bi = c; }
        }
    }
    float cv[4];
    #pragma unroll
    for (int j = 0; j < 4; ++j) {
        int c = lane + 64 * j;
        cv[j] = __shfl(aw, c >> 4) + __shfl(bw, c & 15);
    }
    int myidx = 0; float myw = 0.f;
    for (int i = 0; i < 16; ++i) {
        float v = cv[0]; int c = lane;
        #pragma unroll
        for (int j = 1; j < 4; ++j) { int cc = lane + 64 * j; if (cv[j] > v) { v = cv[j]; c = cc; } }
        #pragma unroll
        for (int m = 32; m >= 1; m >>= 1) {
            float ov = __shfl_xor(v, m); int oc = __shfl_xor(c, m);
            if (ov > v || (ov == v && oc < c)) { v = ov; c = oc; }
        }
        #pragma unroll
        for (int j = 0; j < 4; ++j) if (c == lane + 64 * j) cv[j] = -INFINITY;
        int p = c >> 4, q = c & 15;
        int ex = __shfl(ai, p);
        int ey = __shfl(bi, q);
        if (lane == i) { myidx = ex * 128 + ey; myw = __expf(v); }
    }
    if (lane < 16) {
        oidx[t * TOPK + lane] = myidx;
        owt[t * TOPK + lane]  = myw;
    }
}

// ---------------- expert gather/combine (bf16 tables + bf16 x) ----------------
__global__ __launch_bounds__(256)
void expert_combine(const unsigned short* __restrict__ xb, const int* __restrict__ idx,
                    const float* __restrict__ wts, const unsigned short* __restrict__ ueb,
                    const unsigned short* __restrict__ deb, float* __restrict__ out) {
    const int t = blockIdx.x;
    const int tid = threadIdx.x;
    const int lane = tid & 63, wv = tid >> 6;
    __shared__ float part[TOPK * 4];
    __shared__ float sc[TOPK];
    ushort4 xv4 = ((const ushort4*)(xb + (size_t)t * HDIM))[tid];
    float x0 = bf2f(xv4.x), x1 = bf2f(xv4.y), x2 = bf2f(xv4.z), x3 = bf2f(xv4.w);
    int e[TOPK];
    #pragma unroll
    for (int k = 0; k < TOPK; ++k) e[k] = idx[t * TOPK + k];
    #pragma unroll
    for (int k = 0; k < TOPK; ++k) {
        ushort4 u4 = ((const ushort4*)(ueb + (size_t)e[k] * HDIM))[tid];
        float p = bf2f(u4.x) * x0 + bf2f(u4.y) * x1 + bf2f(u4.z) * x2 + bf2f(u4.w) * x3;
        #pragma unroll
        for (int m = 32; m >= 1; m >>= 1) p += __shfl_xor(p, m);
        if (lane == 0) part[k * 4 + wv] = p;
    }
    __syncthreads();
    if (tid < TOPK) {
        float s = part[tid * 4] + part[tid * 4 + 1] + part[tid * 4 + 2] + part[tid * 4 + 3];
        sc[tid] = s * wts[t * TOPK + tid];
    }
    __syncthreads();
    float4 acc = {0.f, 0.f, 0.f, 0.f};
    #pragma unroll
    for (int k = 0; k < TOPK; ++k) {
        float s = sc[k];
        ushort4 d4 = ((const ushort4*)(deb + (size_t)e[k] * HDIM))[tid];
        acc.x += s * bf2f(d4.x); acc.y += s * bf2f(d4.y);
        acc.z += s * bf2f(d4.z); acc.w += s * bf2f(d4.w);
    }
    ((float4*)(out + (size_t)t * HDIM))[tid] = acc;
}

extern "C" void kernel_launch(void* const* d_in, const int* in_sizes, int n_in,
                              void* d_out, int out_size, void* d_ws, size_t ws_size,
                              hipStream_t stream) {
    const float* x  = (const float*)d_in[0];
    const float* gw = (const float*)d_in[1];
    const float* uw = (const float*)d_in[2];
    const float* dw = (const float*)d_in[3];
    const float* wx = (const float*)d_in[4];
    const float* wy = (const float*)d_in[5];
    const float* ue = (const float*)d_in[6];
    const float* de = (const float*)d_in[7];
    float* out = (float*)d_out;

    char* ws = (char*)d_ws;
    size_t o = 0;
    auto alloc = [&](size_t bytes) { void* p = ws + o; o += (bytes + 255) & ~(size_t)255; return p; };
    unsigned short* xb    = (unsigned short*)alloc((size_t)T_TOK * HDIM * 2);
    unsigned short* gateb = (unsigned short*)alloc((size_t)IDIM * HDIM * 2);
    unsigned short* upb   = (unsigned short*)alloc((size_t)IDIM * HDIM * 2);
    unsigned short* downb = (unsigned short*)alloc((size_t)HDIM * IDIM * 2);
    unsigned short* wrb   = (unsigned short*)alloc((size_t)256 * HDIM * 2);
    unsigned short* ueb   = (unsigned short*)alloc((size_t)16384 * HDIM * 2);
    unsigned short* deb   = (unsigned short*)alloc((size_t)16384 * HDIM * 2);
    unsigned short* hbuf  = (unsigned short*)alloc((size_t)T_TOK * IDIM * 2);
    float* gxy  = (float*)alloc((size_t)T_TOK * 256 * 4);
    float* sums = (float*)alloc(256 * 4);
    float* ssq  = (float*)alloc(256 * 4);
    int*   idxs = (int*)alloc((size_t)T_TOK * TOPK * 4);
    float* wts  = (float*)alloc((size_t)T_TOK * TOPK * 4);

    // merged converts (8 segments)
    CvtSegs segs;
    const float* srcs[8] = {x, gw, uw, dw, wx, wy, ue, de};
    unsigned short* dsts[8] = {xb, gateb, upb, downb, wrb, wrb + SDIM * HDIM, ueb, deb};
    const int cnt4[8] = {T_TOK * HDIM / 4, IDIM * HDIM / 4, IDIM * HDIM / 4, IDIM * HDIM / 4,
                         SDIM * HDIM / 4, SDIM * HDIM / 4, 16384 * HDIM / 4, 16384 * HDIM / 4};
    int acc = 0;
    for (int i = 0; i < 8; ++i) {
        segs.src[i] = (const float4*)srcs[i];
        segs.dst[i] = (ushort4*)dsts[i];
        acc += cnt4[i];
        segs.end[i] = acc;
    }
    cvt_all_kernel<<<(acc + 255) / 256, 256, 0, stream>>>(segs);

    hipMemsetAsync(sums, 0, 2 * 256 * 4, stream);  // sums+ssq contiguous

    // fused MLP-up + router logits (router tiles: by in [64,68))
    gemm1_fused<<<dim3(T_TOK / 128, IDIM / 64 + 4), 256, 0, stream>>>(xb, gateb, upb, wrb, hbuf, gxy);

    bn_stats<<<256, 256, 0, stream>>>(gxy, sums, ssq);
    routing_kernel<<<T_TOK / 4, 256, 0, stream>>>(gxy, sums, ssq, idxs, wts);

    // expert branch writes out fully
    expert_combine<<<T_TOK, 256, 0, stream>>>(xb, idxs, wts, ueb, deb, out);

    // down-proj accumulates on top
    gemm2_add<<<dim3(T_TOK / 128, HDIM / 128), 256, 0, stream>>>(hbuf, downb, out);
}